// Round 1
// 1237.566 us; speedup vs baseline: 1.1905x; 1.1905x over previous
//
#include <hip/hip_runtime.h>
#include <cstdint>
#include <cstddef>

#define D 128
#define RR 8
#define LDA 1152   // Abig row: 8*128 agg + 128 h

typedef __attribute__((ext_vector_type(8))) short short8;
typedef __attribute__((ext_vector_type(4))) float f32x4;

__device__ inline ushort f2b(float x) {
    union { float f; unsigned u; } v; v.f = x;
    unsigned r = v.u + 0x7fff + ((v.u >> 16) & 1);
    return (ushort)(r >> 16);
}
__device__ inline float b2f(ushort u) {
    union { unsigned u; float f; } v; v.u = ((unsigned)u) << 16; return v.f;
}

// async global->LDS, 16B per lane; LDS dest = wave-uniform base + lane*16
__device__ inline void gload_lds16(const ushort* g, ushort* l) {
    __builtin_amdgcn_global_load_lds(
        (const __attribute__((address_space(1))) unsigned int*)g,
        (__attribute__((address_space(3))) unsigned int*)l, 16, 0, 0);
}

// ---------------------------------------------------------------------------
// bf16 MFMA GEMM: C[M, ncol] = A[M, ktiles*128] @ B (+bias) (+relu)
// A: [M][lda] bf16 (lda mult of 8).  BT: [128][ktiles*128] bf16, row = out col.
// 256 threads = 4 waves; block tile 128(M) x 128(N); BK=64 (32 KB LDS ->
// 4+ blocks/CU by LDS).  Staging via global_load_lds width=16 (m97 structure):
// LDS layout linear, XOR bank swizzle applied on the per-lane GLOBAL source
// address and the ds_read address (both-sides rule).  OOB tail rows clamp to
// row M-1 (valid memory; never stored).  In-place A==Cb safe: all A reads of
// a block's own rows drain before its epilogue stores.
// ---------------------------------------------------------------------------
template<bool BIAS, bool RELU, bool STF, bool STB>
__global__ __launch_bounds__(256, 4) void gemm_bf16(
    const ushort* __restrict__ A, int lda, const ushort* __restrict__ BT, int ktiles,
    const float* __restrict__ bias, float* __restrict__ Cf, int ldcf,
    ushort* __restrict__ Cb, int ldcb, int M, int ncol)
{
    __shared__ ushort As[128 * 64];
    __shared__ ushort Bs[128 * 64];
    const int tid = threadIdx.x;
    const int m0 = blockIdx.x * 128;
    const int ldb = ktiles * 128;
    const int ksteps = ktiles * 2;          // BK = 64

    const int w = tid >> 6, lane = tid & 63;
    const int wm = (w & 1) * 64, wn = (w >> 1) * 64;
    const int l15 = lane & 15, quad = lane >> 4;

    // staging geometry: per (wave, it) the wave fills LDS groups
    // gi = w*256 + it*64 + lane ; row = gi>>3, g = gi&7 (8 x 16B groups/row).
    // Data at linear LDS group (row,g) must be global col-group g^(row&7).
    const ushort* aptr[4];
    const ushort* bptr[4];
#pragma unroll
    for (int it = 0; it < 4; it++) {
        int gi = w * 256 + it * 64 + lane;
        int row = gi >> 3, g = gi & 7;
        int cg = g ^ (row & 7);
        int gr = m0 + row; if (gr > M - 1) gr = M - 1;   // clamp tail
        aptr[it] = A + (size_t)gr * lda + (cg << 3);
        bptr[it] = BT + (size_t)row * ldb + (cg << 3);   // B rows 0..127 always allocated
    }

    f32x4 acc[4][4];
    const f32x4 z4 = {0.f, 0.f, 0.f, 0.f};
#pragma unroll
    for (int i = 0; i < 4; i++)
#pragma unroll
        for (int j = 0; j < 4; j++) acc[i][j] = z4;

    for (int kt = 0; kt < ksteps; kt++) {
        const int ko = kt * 64;
#pragma unroll
        for (int it = 0; it < 4; it++)
            gload_lds16(aptr[it] + ko, As + w * 2048 + it * 512);
#pragma unroll
        for (int it = 0; it < 4; it++)
            gload_lds16(bptr[it] + ko, Bs + w * 2048 + it * 512);
        __syncthreads();   // compiler emits vmcnt(0) drain before barrier

#pragma unroll
        for (int ks = 0; ks < 64; ks += 32) {
            const int q0 = (ks >> 3) + quad;        // k-group 0..7
            short8 af[4], bfr[4];
#pragma unroll
            for (int i = 0; i < 4; i++) {
                int row = wm + i * 16 + l15;
                af[i] = *(const short8*)(&As[row * 64 + ((q0 ^ (row & 7)) << 3)]);
            }
#pragma unroll
            for (int j = 0; j < 4; j++) {
                int row = wn + j * 16 + l15;
                bfr[j] = *(const short8*)(&Bs[row * 64 + ((q0 ^ (row & 7)) << 3)]);
            }
#pragma unroll
            for (int i = 0; i < 4; i++)
#pragma unroll
                for (int j = 0; j < 4; j++)
                    acc[i][j] = __builtin_amdgcn_mfma_f32_16x16x32_bf16(
                        af[i], bfr[j], acc[i][j], 0, 0, 0);
        }
        __syncthreads();
    }

    // epilogue: C[m=quad*4+q][n=l15] per 16x16 frag
#pragma unroll
    for (int i = 0; i < 4; i++) {
#pragma unroll
        for (int q = 0; q < 4; q++) {
            int gm = m0 + wm + i * 16 + quad * 4 + q;
            if (gm >= M) continue;
#pragma unroll
            for (int j = 0; j < 4; j++) {
                int gn = wn + j * 16 + l15;
                if (gn >= ncol) continue;
                float v = acc[i][j][q];
                if (BIAS) v += bias[gn];
                if (RELU) v = v > 0.f ? v : 0.f;
                if (STF) Cf[(size_t)gm * ldcf + gn] = v;
                if (STB) Cb[(size_t)gm * ldcb + gn] = f2b(v);
            }
        }
    }
}

// ---------------------------------------------------------------------------
// bigBT[f][c]: c<1024 -> W_{c>>7}[c&127][f];  c>=1024 -> root[c-1024][f]
// ---------------------------------------------------------------------------
__global__ void build_bigBT(const float* __restrict__ basis,
                            const float* __restrict__ comp,
                            const float* __restrict__ root,
                            ushort* __restrict__ BT)
{
    int i = blockIdx.x * 256 + threadIdx.x;
    if (i >= 128 * LDA) return;
    int f = i / LDA, c = i - f * LDA;
    float a;
    if (c < 1024) {
        int r = c >> 7, d = c & 127;
        a = 0.f;
#pragma unroll
        for (int b = 0; b < 4; b++)
            a += comp[r * 4 + b] * basis[(b * 128 + d) * 128 + f];
    } else {
        a = root[(c - 1024) * 128 + f];
    }
    BT[i] = f2b(a);
}

// out[f*128+k] = bf16(in[k*cols+f]) for f<cols else 0   (in: [128][cols])
__global__ void transpose_pad(const float* __restrict__ in, ushort* __restrict__ out,
                              int cols)
{
    int i = blockIdx.x * 256 + threadIdx.x;
    if (i >= 128 * 128) return;
    int k = i & 127, f = i >> 7;
    out[i] = (f < cols) ? f2b(in[k * cols + f]) : (ushort)0;
}

// x [N][128] fp32 -> Abig h-block bf16
__global__ void cast_x(const float* __restrict__ in, ushort* __restrict__ Abig, int total4)
{
    int i = blockIdx.x * 256 + threadIdx.x;
    if (i >= total4) return;
    int n = i >> 5, q = i & 31;
    float4 v = ((const float4*)in)[i];
    ushort4 o = { f2b(v.x), f2b(v.y), f2b(v.z), f2b(v.w) };
    *(ushort4*)(Abig + (size_t)n * LDA + 1024 + q * 4) = o;
}

// ---------------------------------------------------------------------------
__global__ void count_edges(const int* __restrict__ src, const int* __restrict__ dst,
                            const int* __restrict__ et, int* __restrict__ cnt,
                            int* __restrict__ deg, int E)
{
    int e0 = (blockIdx.x * 256 + threadIdx.x) * 4;
#pragma unroll
    for (int j = 0; j < 4; j++) {
        int e = e0 + j;
        if (e < E) {
            atomicAdd(&cnt[dst[e] * RR + et[e]], 1);
            atomicAdd(&deg[src[e]], 1);
        }
    }
}

// ---------------------------------------------------------------------------
// 3-phase exclusive scan (1024 elements per block)
// ---------------------------------------------------------------------------
__global__ void scan1(const int* __restrict__ in, int* __restrict__ bsum, int n)
{
    __shared__ int s[256];
    const int b = blockIdx.x, t = threadIdx.x;
    const int base = b * 1024;
    int v = 0;
#pragma unroll
    for (int i = 0; i < 4; i++) {
        int idx = base + t * 4 + i;
        if (idx < n) v += in[idx];
    }
    s[t] = v; __syncthreads();
    for (int off = 128; off > 0; off >>= 1) {
        if (t < off) s[t] += s[t + off];
        __syncthreads();
    }
    if (t == 0) bsum[b] = s[0];
}

__global__ void scan_top(int* __restrict__ bsum, int nb)
{
    __shared__ int s[1024];
    const int t = threadIdx.x;
    int v = (t < nb) ? bsum[t] : 0;
    s[t] = v; __syncthreads();
    for (int off = 1; off < 1024; off <<= 1) {
        int x = (t >= off) ? s[t - off] : 0;
        __syncthreads();
        s[t] += x;
        __syncthreads();
    }
    if (t < nb) bsum[t] = s[t] - v;   // exclusive
}

__global__ void scan2(const int* __restrict__ in, const int* __restrict__ bsum,
                      int* __restrict__ out, int n)
{
    __shared__ int s[256];
    const int b = blockIdx.x, t = threadIdx.x;
    const int base = b * 1024;
    int loc[4];
    int v = 0;
#pragma unroll
    for (int i = 0; i < 4; i++) {
        int idx = base + t * 4 + i;
        int x = (idx < n) ? in[idx] : 0;
        loc[i] = v; v += x;
    }
    s[t] = v; __syncthreads();
    for (int off = 1; off < 256; off <<= 1) {
        int x = (t >= off) ? s[t - off] : 0;
        __syncthreads();
        s[t] += x;
        __syncthreads();
    }
    const int add = bsum[b] + (s[t] - v);
#pragma unroll
    for (int i = 0; i < 4; i++) {
        int idx = base + t * 4 + i;
        if (idx < n) out[idx] = add + loc[i];
    }
}

// ---------------------------------------------------------------------------
// both CSR fills in one pass
// ---------------------------------------------------------------------------
__global__ void fill_both(const int* __restrict__ src, const int* __restrict__ dst,
                          const int* __restrict__ et,
                          const int* __restrict__ aoff, int* __restrict__ acur,
                          int* __restrict__ acsr,
                          const int* __restrict__ goff, int* __restrict__ gcur,
                          int* __restrict__ gcsr, int E)
{
    int e0 = (blockIdx.x * 256 + threadIdx.x) * 4;
#pragma unroll
    for (int j = 0; j < 4; j++) {
        int e = e0 + j;
        if (e < E) {
            int s0 = src[e], d0 = dst[e];
            int seg = d0 * RR + et[e];
            int p = aoff[seg] + atomicAdd(&acur[seg], 1);
            acsr[p] = s0;
            int pg = goff[s0] + atomicAdd(&gcur[s0], 1);
            gcsr[pg] = d0;
        }
    }
}

// ---------------------------------------------------------------------------
// gate gather (bf16 h): TAUb[n] = bf16(tanh( mean_out-edges (h[n]-h[dst])^2 ))
// ---------------------------------------------------------------------------
__global__ __launch_bounds__(256) void gate_gather(
    const ushort* __restrict__ Abig, const int* __restrict__ gcsr,
    const int* __restrict__ goff, const int* __restrict__ deg,
    ushort* __restrict__ TAUb, int N)
{
    const int g = threadIdx.x >> 5, lane = threadIdx.x & 31;
    const int n = blockIdx.x * 8 + g;
    if (n >= N) return;
    const int start = goff[n];
    const int c = deg[n];
    const ushort* hbase = Abig + 1024 + lane * 4;
    ushort4 a4 = *(const ushort4*)(hbase + (size_t)n * LDA);
    float ax = b2f(a4.x), ay = b2f(a4.y), az = b2f(a4.z), aw = b2f(a4.w);
    float4 acc = {0.f, 0.f, 0.f, 0.f};
    int i = 0;
    for (; i + 2 <= c; i += 2) {
        int d0 = gcsr[start + i], d1 = gcsr[start + i + 1];
        ushort4 b0 = *(const ushort4*)(hbase + (size_t)d0 * LDA);
        ushort4 b1 = *(const ushort4*)(hbase + (size_t)d1 * LDA);
        float dx = ax - b2f(b0.x), dy = ay - b2f(b0.y),
              dz = az - b2f(b0.z), dw = aw - b2f(b0.w);
        acc.x += dx * dx; acc.y += dy * dy; acc.z += dz * dz; acc.w += dw * dw;
        dx = ax - b2f(b1.x); dy = ay - b2f(b1.y);
        dz = az - b2f(b1.z); dw = aw - b2f(b1.w);
        acc.x += dx * dx; acc.y += dy * dy; acc.z += dz * dz; acc.w += dw * dw;
    }
    if (i < c) {
        int d0 = gcsr[start + i];
        ushort4 b0 = *(const ushort4*)(hbase + (size_t)d0 * LDA);
        float dx = ax - b2f(b0.x), dy = ay - b2f(b0.y),
              dz = az - b2f(b0.z), dw = aw - b2f(b0.w);
        acc.x += dx * dx; acc.y += dy * dy; acc.z += dz * dz; acc.w += dw * dw;
    }
    const float inv = (c > 0) ? (1.f / (float)c) : 1.f;
    ushort4 t;
    t.x = f2b(tanhf(acc.x * inv)); t.y = f2b(tanhf(acc.y * inv));
    t.z = f2b(tanhf(acc.z * inv)); t.w = f2b(tanhf(acc.w * inv));
    *(ushort4*)(TAUb + (size_t)n * D + lane * 4) = t;
}

// ---------------------------------------------------------------------------
// agg gather: Abig[n][r*128+f] = mean_{e in seg(n,r)} h_bf16[src_e][f]  (0 if empty)
// one 32-lane group per segment
// ---------------------------------------------------------------------------
__global__ __launch_bounds__(256) void agg_gather(
    ushort* __restrict__ Abig, const int* __restrict__ acsr,
    const int* __restrict__ aoff, const int* __restrict__ cnt, int Nseg)
{
    const int g = threadIdx.x >> 5, lane = threadIdx.x & 31;
    const int s = blockIdx.x * 8 + g;
    if (s >= Nseg) return;
    const int n = s >> 3, r = s & 7;
    const int c = cnt[s];
    ushort4 outv = {0, 0, 0, 0};
    if (c > 0) {
        const int st = aoff[s];
        const ushort* hbase = Abig + 1024 + lane * 4;
        float4 acc = {0.f, 0.f, 0.f, 0.f};
        int i = 0;
        for (; i + 2 <= c; i += 2) {
            int s0 = acsr[st + i], s1 = acsr[st + i + 1];
            ushort4 y0 = *(const ushort4*)(hbase + (size_t)s0 * LDA);
            ushort4 y1 = *(const ushort4*)(hbase + (size_t)s1 * LDA);
            acc.x += b2f(y0.x) + b2f(y1.x); acc.y += b2f(y0.y) + b2f(y1.y);
            acc.z += b2f(y0.z) + b2f(y1.z); acc.w += b2f(y0.w) + b2f(y1.w);
        }
        if (i < c) {
            int s0 = acsr[st + i];
            ushort4 y0 = *(const ushort4*)(hbase + (size_t)s0 * LDA);
            acc.x += b2f(y0.x); acc.y += b2f(y0.y);
            acc.z += b2f(y0.z); acc.w += b2f(y0.w);
        }
        const float inv = 1.f / (float)c;
        outv.x = f2b(acc.x * inv); outv.y = f2b(acc.y * inv);
        outv.z = f2b(acc.z * inv); outv.w = f2b(acc.w * inv);
    }
    *(ushort4*)(Abig + (size_t)n * LDA + r * 128 + lane * 4) = outv;
}

// ---------------------------------------------------------------------------
// h_next = (1-tau)*h + tau*hn  (hn already relu'd by GEMM epilogue);
// writes fp32 hn and bf16 into Abig h-block
// ---------------------------------------------------------------------------
__global__ void finalize(const float* __restrict__ hp, float* __restrict__ hn,
                         const ushort* __restrict__ TAUb, ushort* __restrict__ Abig,
                         int total4)
{
    int idx = blockIdx.x * 256 + threadIdx.x;
    if (idx >= total4) return;
    int n = idx >> 5, q = idx & 31;
    const float4 p = ((const float4*)hp)[idx];
    const float4 a = ((const float4*)hn)[idx];
    const ushort4 t4 = ((const ushort4*)TAUb)[idx];
    float4 o;
    o.x = p.x + b2f(t4.x) * (a.x - p.x);
    o.y = p.y + b2f(t4.y) * (a.y - p.y);
    o.z = p.z + b2f(t4.z) * (a.z - p.z);
    o.w = p.w + b2f(t4.w) * (a.w - p.w);
    ((float4*)hn)[idx] = o;
    ushort4 ob = { f2b(o.x), f2b(o.y), f2b(o.z), f2b(o.w) };
    *(ushort4*)(Abig + (size_t)n * LDA + 1024 + q * 4) = ob;
}

// ---------------------------------------------------------------------------
extern "C" void kernel_launch(void* const* d_in, const int* in_sizes, int n_in,
                              void* d_out, int out_size, void* d_ws, size_t ws_size,
                              hipStream_t stream)
{
    const float* x      = (const float*)d_in[0];
    const int*   src    = (const int*)  d_in[1];
    const int*   dst    = (const int*)  d_in[2];
    const int*   etyp   = (const int*)  d_in[3];
    const float* projW  = (const float*)d_in[4];
    const float* projb  = (const float*)d_in[5];
    const float* basis1 = (const float*)d_in[6];
    const float* comp1  = (const float*)d_in[7];
    const float* root1  = (const float*)d_in[8];
    const float* bias1  = (const float*)d_in[9];
    const float* basis2 = (const float*)d_in[10];
    const float* comp2  = (const float*)d_in[11];
    const float* root2  = (const float*)d_in[12];
    const float* bias2  = (const float*)d_in[13];
    const float* outW   = (const float*)d_in[14];
    const float* outb   = (const float*)d_in[15];

    const int N    = in_sizes[0] / D;
    const int E    = in_sizes[1];
    const int OUTD = in_sizes[15];

    float* out  = (float*)d_out;
    float* lat0 = out + (size_t)N * OUTD;
    float* lat1 = lat0 + (size_t)N * D;
    float* lat2 = lat1 + (size_t)N * D;

    // ---- workspace layout ----
    char* p = (char*)d_ws;
    ushort* Abig  = (ushort*)p;  p += (size_t)N * LDA * 2;
    ushort* TAUb  = (ushort*)p;  p += (size_t)N * D * 2;
    ushort* projWT = (ushort*)p; p += 16384 * 2;
    ushort* outWT  = (ushort*)p; p += 16384 * 2;
    ushort* bigBT1 = (ushort*)p; p += (size_t)128 * LDA * 2;
    ushort* bigBT2 = (ushort*)p; p += (size_t)128 * LDA * 2;
    int* cnt_i  = (int*)p;       p += (size_t)N * RR * 4;
    int* deg_i  = (int*)p;       p += (size_t)N * 4;
    int* acur   = (int*)p;       p += (size_t)N * RR * 4;
    int* gcur   = (int*)p;       p += (size_t)N * 4;
    int* aoff   = (int*)p;       p += (size_t)N * RR * 4;
    int* goff   = (int*)p;       p += (size_t)N * 4;
    int* acsr   = (int*)p;       p += (size_t)E * 4;
    int* gcsr   = (int*)p;       p += (size_t)E * 4;
    int* bsum   = (int*)p;       p += 4096;

    if ((size_t)(p - (char*)d_ws) > ws_size) return;  // fails loudly

    // zero counters (cnt_i, deg_i, acur, gcur contiguous)
    hipMemsetAsync(cnt_i, 0, sizeof(int) * 2 * ((size_t)N * RR + N), stream);

    // weight prep
    build_bigBT<<<(128 * LDA + 255) / 256, 256, 0, stream>>>(basis1, comp1, root1, bigBT1);
    build_bigBT<<<(128 * LDA + 255) / 256, 256, 0, stream>>>(basis2, comp2, root2, bigBT2);
    transpose_pad<<<64, 256, 0, stream>>>(projW, projWT, 128);
    transpose_pad<<<64, 256, 0, stream>>>(outW, outWT, OUTD);

    cast_x<<<(N * 32 + 255) / 256, 256, 0, stream>>>(x, Abig, N * 32);

    count_edges<<<(E / 4 + 255) / 256, 256, 0, stream>>>(src, dst, etyp, cnt_i, deg_i, E);

    {   // exclusive scans -> CSR offsets
        int n1 = N * RR, nb1 = (n1 + 1023) / 1024;
        scan1<<<nb1, 256, 0, stream>>>(cnt_i, bsum, n1);
        scan_top<<<1, 1024, 0, stream>>>(bsum, nb1);
        scan2<<<nb1, 256, 0, stream>>>(cnt_i, bsum, aoff, n1);
        int nb2 = (N + 1023) / 1024;
        scan1<<<nb2, 256, 0, stream>>>(deg_i, bsum, N);
        scan_top<<<1, 1024, 0, stream>>>(bsum, nb2);
        scan2<<<nb2, 256, 0, stream>>>(deg_i, bsum, goff, N);
    }

    fill_both<<<(E / 4 + 255) / 256, 256, 0, stream>>>(
        src, dst, etyp, aoff, acur, acsr, goff, gcur, gcsr, E);

    const int mb = (N + 127) / 128;
    const int nodeblocks = (N + 7) / 8;
    const int segblocks = (N * RR + 7) / 8;

    // proj: lat0 = relu(x @ projW + projb); bf16 -> Abig h-block (in-place safe)
    gemm_bf16<true, true, true, true><<<mb, 256, 0, stream>>>(
        Abig + 1024, LDA, projWT, 1, projb, lat0, 128, Abig + 1024, LDA, N, 128);

    const ushort* bigBT[2] = {bigBT1, bigBT2};
    const float* biases[2] = {bias1, bias2};
    float* lats[3]         = {lat0, lat1, lat2};

    for (int l = 0; l < 2; l++) {
        float* hn = lats[l + 1];

        gate_gather<<<nodeblocks, 256, 0, stream>>>(Abig, gcsr, goff, deg_i, TAUb, N);
        agg_gather<<<segblocks, 256, 0, stream>>>(Abig, acsr, aoff, cnt_i, N * RR);

        // hn = relu(Abig @ [W_1..W_8; root] + bias)
        gemm_bf16<true, true, true, false><<<mb, 256, 0, stream>>>(
            Abig, LDA, bigBT[l], 9, biases[l], hn, 128, nullptr, 0, N, 128);

        finalize<<<(N * 32 + 255) / 256, 256, 0, stream>>>(
            lats[l], hn, TAUb, Abig, N * 32);
    }

    // out = lat2 @ outW + outb
    gemm_bf16<true, false, true, false><<<mb, 256, 0, stream>>>(
        Abig + 1024, LDA, outWT, 1, outb, out, OUTD, nullptr, 0, N, OUTD);
}